// Round 2
// baseline (3947.009 us; speedup 1.0000x reference)
//
#include <hip/hip_runtime.h>

// Dims
constexpr int TSTEPS = 512;
constexpr int FDIM   = 128;
constexpr int HDIM   = 256;
constexpr int G4H    = 1024;   // 4*H
constexpr int TC     = 8;      // time-chunk (xz granularity)
constexpr int NCH    = TSTEPS / TC;

typedef float        f32x2 __attribute__((ext_vector_type(2)));
typedef _Float16     h2    __attribute__((ext_vector_type(2)));
typedef unsigned int u32;
typedef u32          u32x2 __attribute__((ext_vector_type(2)));
typedef u32          u32x4 __attribute__((ext_vector_type(4)));

#if defined(__has_builtin)
#if __has_builtin(__builtin_amdgcn_fdot2)
#define FDOT2(a, b, c) __builtin_amdgcn_fdot2((a), (b), (c), false)
#endif
#endif
#ifndef FDOT2
#define FDOT2(a, b, c) ((c) + (float)(a)[0] * (float)(b)[0] + (float)(a)[1] * (float)(b)[1])
#endif

__device__ __forceinline__ h2 as_h2(u32 v) { union { u32 u; h2 p; } c; c.u = v; return c.p; }
__device__ __forceinline__ u32 pack_h2(float a, float b) {
    union { h2 p; u32 u; } c; c.p = h2{(_Float16)a, (_Float16)b}; return c.u;
}
__device__ __forceinline__ float sigmf(float z) { return 1.f / (1.f + __expf(-z)); }
__device__ __forceinline__ float tanhf_fast(float z) {
    float a = fabsf(z);
    float e = __expf(-2.f * a);
    float r = (1.f - e) / (1.f + e);
    return z < 0.f ? -r : r;
}

// ws layout (u32): [0]=wcount, [16..272)=flags, [512..) WG weights (4x32768),
// HX (2x64x512) overlays WG[0..65536) — guarded by the wcount barrier.
// All cross-block traffic uses RELAXED sc1 atomics (MALL-direct): no acquire
// invalidates, no release writebacks. Visibility chain: HX stores -> B3
// __syncthreads drains vmcnt(0) (acked at MALL) -> relaxed flag store ->
// partner's relaxed poll sees flag -> its later sc1 loads see HX at MALL.

extern "C" __global__ void __launch_bounds__(256)
conv_wpk(const float* __restrict__ rker, u32* __restrict__ ws)
{
    for (int i = blockIdx.x * 256 + threadIdx.x; i < 512 + 4 * 32768; i += gridDim.x * 256) {
        if (i < 512) { ws[i] = 0; continue; }   // zero wcount + flags (every launch)
        const int ii  = i - 512;
        const int q   = ii >> 15, j = ii & 32767;
        const int kp2 = j >> 9,  rem = j & 511;
        const int c   = rem >> 1, par = rem & 1;
        const int kp  = 2 * kp2 + par;
        const int gcol = (c >> 6) * 256 + 64 * q + (c & 63);
        const float a = rker[(size_t)(2 * kp) * G4H + gcol];
        const float b = rker[(size_t)(2 * kp + 1) * G4H + gcol];
        ws[i] = pack_h2(a, b);
    }
}

// 8-fp-pair xz slice: accumulates into register acc[tp][r]; identical FLOP
// order to the old burst (fp ascending), just split across the 8 steps.
__device__ __forceinline__ void slice8(const float* __restrict__ kern, const u32* xs,
                                       int gcol, int half, int fp0, float acc[4][4])
{
#pragma unroll
    for (int u = 0; u < 8; ++u) {
        const int fp = fp0 + u;
        const float k0 = kern[(size_t)(2 * fp) * G4H + gcol];
        const float k1 = kern[(size_t)(2 * fp + 1) * G4H + gcol];
        const h2 wp = h2{(_Float16)k0, (_Float16)k1};
#pragma unroll
        for (int r = 0; r < 4; ++r) {
            const u32x4 X = *reinterpret_cast<const u32x4*>(&xs[fp * 32 + r * 8 + half * 4]);
#pragma unroll
            for (int tp = 0; tp < 4; ++tp)
                acc[tp][r] = FDOT2(wp, as_h2(X[tp]), acc[tp][r]);
        }
    }
}

extern "C" __global__ void __launch_bounds__(512)
lstm_pers(const float* __restrict__ x, const float* __restrict__ kern,
          u32* __restrict__ ws,
          const float* __restrict__ w1, const float* __restrict__ b1,
          const float* __restrict__ w2, const float* __restrict__ b2,
          float* __restrict__ out)
{
    const int bid = blockIdx.x;
    const int g   = bid & 63;        // group: rows [4g, 4g+4)
    const int q   = bid >> 6;        // member: units [64q, 64q+64)
    const int tid = threadIdx.x;

    u32*       const FLG = ws + 16;
    const u32* const WG  = ws + 512;
    u32*       const HX  = ws + 512;  // overlays WG (guarded by wcount barrier)

    // LDS: 131072 + 16384 + 8192 + 4096 + 2048 = 161,792 B (<= 160 KiB, 1 blk/CU)
    __shared__ __align__(16) u32   wl[32768];    // rker slice [kp2][c][par]
    __shared__ __align__(16) u32   xzp[4096];    // xz fp16 row-pairs [rp][t][c]
    __shared__ __align__(16) u32   xs[2048];     // x fp16 f-pairs [fp][r][t] (chunk ch+1)
    __shared__ __align__(16) float zbuf[1024];   // z accumulation [r][c] via ds_add
    __shared__ __align__(16) u32   hpk[512];     // h fp16 unit-pairs [kp][row]
    float* const hid = zbuf;                     // head overlay (after final barrier)

    // ---- One-time: weights -> LDS, state init, all-blocks-loaded barrier
    {
        const u32* wsrc = WG + q * 32768;
        for (int i = 4 * tid; i < 32768; i += 4 * 512)
            *reinterpret_cast<u32x4*>(&wl[i]) = *reinterpret_cast<const u32x4*>(&wsrc[i]);
    }
    hpk[tid] = 0;
    zbuf[tid] = 0.f; zbuf[tid + 512] = 0.f;
    __syncthreads();  // WG reads + inits drained before signalling
    if (tid == 0) {
        atomicAdd(&ws[0], 1u);
        while (__hip_atomic_load(&ws[0], __ATOMIC_RELAXED, __HIP_MEMORY_SCOPE_AGENT) < 256u) {}
    }
    __syncthreads();

    const int c    = tid & 255;       // dot column (member-local)
    const int half = tid >> 8;        // K-half
    const int gu   = tid & 63;        // gating unit (local), tid<256
    const int gr   = tid >> 6;        // gating row, tid<256
    const int gcol = (c >> 6) * 256 + 64 * q + (c & 63);
    float cst = 0.f;
    float acc[4][4];                  // xz accumulators for chunk ch+1

    // ---- Prologue: stage x(chunk 0), burst-compute xz(chunk 0)
#pragma unroll
    for (int i = 0; i < 4; ++i) {
        const int slot = tid + i * 512;
        const int rt = slot >> 6, fp = slot & 63;
        const int r = rt >> 3, t = rt & 7;
        const f32x2 xv = *reinterpret_cast<const f32x2*>(
            &x[(((size_t)(4 * g + r)) * TSTEPS + t) * FDIM + 2 * fp]);
        xs[fp * 32 + r * 8 + t] = pack_h2(xv[0], xv[1]);
    }
    __syncthreads();
#pragma unroll
    for (int tp = 0; tp < 4; ++tp)
#pragma unroll
        for (int r = 0; r < 4; ++r) acc[tp][r] = 0.f;
#pragma unroll 1
    for (int s8 = 0; s8 < 8; ++s8) slice8(kern, xs, gcol, half, 8 * s8, acc);
#pragma unroll
    for (int tp = 0; tp < 4; ++tp)
#pragma unroll
        for (int rp = 0; rp < 2; ++rp)
            xzp[rp * 2048 + (half * 4 + tp) * 256 + c] =
                pack_h2(acc[tp][2 * rp], acc[tp][2 * rp + 1]);

#pragma unroll 1
    for (int ch = 0; ch < NCH; ++ch) {
        __syncthreads();  // SA0: prev-chunk slices done (xs free), xzp(ch) written

        if (ch < NCH - 1) {  // stage x(ch+1) for this chunk's slices
#pragma unroll
            for (int i = 0; i < 4; ++i) {
                const int slot = tid + i * 512;
                const int rt = slot >> 6, fp = slot & 63;
                const int r = rt >> 3, t = rt & 7;
                const f32x2 xv = *reinterpret_cast<const f32x2*>(
                    &x[(((size_t)(4 * g + r)) * TSTEPS + ((ch + 1) * TC + t)) * FDIM + 2 * fp]);
                xs[fp * 32 + r * 8 + t] = pack_h2(xv[0], xv[1]);
            }
        }
#pragma unroll
        for (int tp = 0; tp < 4; ++tp)
#pragma unroll
            for (int r = 0; r < 4; ++r) acc[tp][r] = 0.f;

#pragma unroll 1
        for (int tc = 0; tc < TC; ++tc) {
            const int t = ch * TC + tc;
            __syncthreads();  // B1: hpk(t) complete (imports done), zbuf zeroed, xs staged

            u32 xz4[4];
            if (tid < 256) {  // preload xz before B2 (slice writers touch xzp post-B2 @tc=7)
#pragma unroll
                for (int g4 = 0; g4 < 4; ++g4)
                    xz4[g4] = xzp[(gr >> 1) * 2048 + tc * 256 + g4 * 64 + gu];
            }

            float a0 = 0.f, a1 = 0.f, a2 = 0.f, a3 = 0.f;
#pragma unroll 8
            for (int kq = 0; kq < 32; ++kq) {
                const int kp2 = half * 32 + kq;
                const u32x2 W  = *reinterpret_cast<const u32x2*>(&wl[kp2 * 512 + 2 * c]);
                const u32x4 H0 = *reinterpret_cast<const u32x4*>(&hpk[(2 * kp2) * 4]);
                const u32x4 H1 = *reinterpret_cast<const u32x4*>(&hpk[(2 * kp2 + 1) * 4]);
                const h2 w0 = as_h2(W[0]), w1h = as_h2(W[1]);
                a0 = FDOT2(w0, as_h2(H0[0]), a0); a0 = FDOT2(w1h, as_h2(H1[0]), a0);
                a1 = FDOT2(w0, as_h2(H0[1]), a1); a1 = FDOT2(w1h, as_h2(H1[1]), a1);
                a2 = FDOT2(w0, as_h2(H0[2]), a2); a2 = FDOT2(w1h, as_h2(H1[2]), a2);
                a3 = FDOT2(w0, as_h2(H0[3]), a3); a3 = FDOT2(w1h, as_h2(H1[3]), a3);
            }
            atomicAdd(&zbuf[0 * 256 + c], a0);  // f32 add commutative: bit-identical
            atomicAdd(&zbuf[1 * 256 + c], a1);
            atomicAdd(&zbuf[2 * 256 + c], a2);
            atomicAdd(&zbuf[3 * 256 + c], a3);
            __syncthreads();  // B2: z complete

            if (tid < 256) {  // gate + export; waves 4-7 run their slice meanwhile
                float z[4];
#pragma unroll
                for (int g4 = 0; g4 < 4; ++g4) {
                    const int cc = g4 * 64 + gu;
                    const h2 xp = as_h2(xz4[g4]);
                    z[g4] = zbuf[gr * 256 + cc] + (float)((gr & 1) ? xp[1] : xp[0]);
                }
                cst = sigmf(z[1]) * cst + sigmf(z[0]) * tanhf_fast(z[2]);
                const float hn = sigmf(z[3]) * tanhf_fast(cst);
                const float ho = __shfl_xor(hn, 1);
#pragma unroll
                for (int g4 = 0; g4 < 4; ++g4) zbuf[gr * 256 + g4 * 64 + gu] = 0.f;
                if (!(gu & 1)) {
                    const int kp = 32 * q + (gu >> 1);
                    const u32 hv = pack_h2(hn, ho);
                    hpk[kp * 4 + gr] = hv;
                    __hip_atomic_store(&HX[(size_t)((t & 1) * 64 + g) * 512 + kp * 4 + gr],
                                       hv, __ATOMIC_RELAXED, __HIP_MEMORY_SCOPE_AGENT);
                }
            } else if (ch < NCH - 1) {
                slice8(kern, xs, gcol, half, 8 * tc, acc);  // waves 4-7: bubble fill
                if (tc == TC - 1) {
#pragma unroll
                    for (int tp = 0; tp < 4; ++tp)
#pragma unroll
                        for (int rp = 0; rp < 2; ++rp)
                            xzp[rp * 2048 + (half * 4 + tp) * 256 + c] =
                                pack_h2(acc[tp][2 * rp], acc[tp][2 * rp + 1]);
                }
            }
            __syncthreads();  // B3: HX exports drained to MALL (vmcnt(0) before s_barrier)

            if (tid == 0)  // relaxed: B3 already ordered the data stores
                __hip_atomic_store(&FLG[g * 4 + q], (u32)(t + 1),
                                   __ATOMIC_RELAXED, __HIP_MEMORY_SCOPE_AGENT);
            if (tid < 256 && ch < NCH - 1) {  // waves 0-3: slice overlaps partner polls
                slice8(kern, xs, gcol, half, 8 * tc, acc);
                if (tc == TC - 1) {
#pragma unroll
                    for (int tp = 0; tp < 4; ++tp)
#pragma unroll
                        for (int rp = 0; rp < 2; ++rp)
                            xzp[rp * 2048 + (half * 4 + tp) * 256 + c] =
                                pack_h2(acc[tp][2 * rp], acc[tp][2 * rp + 1]);
                }
            }
            if (tid >= 128) {  // 384 importers; partner index is wave-uniform
                const int k  = tid - 128;
                const int pi = k >> 7, j7 = k & 127;
                const int p  = pi + (pi >= q);
                while (__hip_atomic_load(&FLG[g * 4 + p], __ATOMIC_RELAXED,
                                         __HIP_MEMORY_SCOPE_AGENT) < (u32)(t + 1)) {}
                const int kp = 32 * p + (j7 >> 2), r = j7 & 3;
                hpk[kp * 4 + r] = __hip_atomic_load(
                    &HX[(size_t)((t & 1) * 64 + g) * 512 + kp * 4 + r],
                    __ATOMIC_RELAXED, __HIP_MEMORY_SCOPE_AGENT);
            }
            // next B1 orders hpk imports vs dot reads
        }
    }
    __syncthreads();

    // ---- Fused head: member q emits out[4g+q] = relu(h@w1+b1)@w2 + b2
    if (tid < 100) {
        float aa = b1[tid];
        const _Float16* hph = (const _Float16*)hpk;
#pragma unroll 8
        for (int k = 0; k < HDIM; ++k)
            aa += (float)hph[((k >> 1) * 4 + q) * 2 + (k & 1)] * w1[k * 100 + tid];
        hid[tid] = fmaxf(aa, 0.f);
    }
    __syncthreads();
    if (tid == 0) {
        float v = b2[0];
#pragma unroll 4
        for (int j = 0; j < 100; ++j) v += hid[j] * w2[j];
        out[4 * g + q] = v;
    }
}

extern "C" void kernel_launch(void* const* d_in, const int* in_sizes, int n_in,
                              void* d_out, int out_size, void* d_ws, size_t ws_size,
                              hipStream_t stream)
{
    const float* x    = (const float*)d_in[0];
    const float* kern = (const float*)d_in[1];
    const float* rker = (const float*)d_in[2];
    const float* w1   = (const float*)d_in[3];
    const float* b1   = (const float*)d_in[4];
    const float* w2   = (const float*)d_in[5];
    const float* b2   = (const float*)d_in[6];
    u32* ws = (u32*)d_ws;  // 526,336 B used (< 768 KB proven)

    conv_wpk<<<dim3(514), dim3(256), 0, stream>>>(rker, ws);
    lstm_pers<<<dim3(256), dim3(512), 0, stream>>>(x, kern, ws, w1, b1, w2, b2, (float*)d_out);
}

// Round 3
// 2544.282 us; speedup vs baseline: 1.5513x; 1.5513x over previous
//
#include <hip/hip_runtime.h>

// Dims
constexpr int TSTEPS = 512;
constexpr int FDIM   = 128;
constexpr int HDIM   = 256;
constexpr int G4H    = 1024;   // 4*H
constexpr int TC     = 8;      // time-chunk (xz granularity)
constexpr int NCH    = TSTEPS / TC;

typedef float        f32x2 __attribute__((ext_vector_type(2)));
typedef _Float16     h2    __attribute__((ext_vector_type(2)));
typedef unsigned int u32;
typedef unsigned long long u64;
typedef u32          u32x2 __attribute__((ext_vector_type(2)));
typedef u32          u32x4 __attribute__((ext_vector_type(4)));

#if defined(__has_builtin)
#if __has_builtin(__builtin_amdgcn_fdot2)
#define FDOT2(a, b, c) __builtin_amdgcn_fdot2((a), (b), (c), false)
#endif
#endif
#ifndef FDOT2
#define FDOT2(a, b, c) ((c) + (float)(a)[0] * (float)(b)[0] + (float)(a)[1] * (float)(b)[1])
#endif

__device__ __forceinline__ h2 as_h2(u32 v) { union { u32 u; h2 p; } c; c.u = v; return c.p; }
__device__ __forceinline__ u32 pack_h2(float a, float b) {
    union { h2 p; u32 u; } c; c.p = h2{(_Float16)a, (_Float16)b}; return c.u;
}
__device__ __forceinline__ float sigmf(float z) { return 1.f / (1.f + __expf(-z)); }
__device__ __forceinline__ float tanhf_fast(float z) {
    float a = fabsf(z);
    float e = __expf(-2.f * a);
    float r = (1.f - e) / (1.f + e);
    return z < 0.f ? -r : r;
}

// ws layout (u32): [0],[1]=startup counters, [512..) WG = repacked rker
// (4 members x 32768 u32 = 512 KB). HX (65536 u64 = 512 KB) EXACTLY overlays
// WG — safe: WG fully consumed before counter-barrier 1; HX tag slots zeroed
// before counter-barrier 2; only then does any block poll.
// HX entry = u64 { lo: h fp16 pair, hi: tag = t+1 }. Tag+data in ONE word
// => no separate flag hop, no vmcnt-drain-before-flag. Tags monotone per slot
// (double-buffered by (t+1)&1) => relaxed agent atomics suffice.
//
// WG layout per member q: wl[kp(128)][u(64)][g4(4)] u32, where the u32 is the
// fp16 pair (rker[2kp][gcol], rker[2kp+1][gcol]), gcol = g4*256 + 64q + u.
// => dot thread reads its 4 gate-cols for one kp with ONE ds_read_b128.

extern "C" __global__ void __launch_bounds__(256)
conv_wpk(const float* __restrict__ rker, u32* __restrict__ ws)
{
    for (int i = blockIdx.x * 256 + threadIdx.x; i < 512 + 4 * 32768; i += gridDim.x * 256) {
        if (i < 512) { ws[i] = 0; continue; }   // zero counters (every launch)
        const int ii = i - 512;
        const int q  = ii >> 15, j = ii & 32767;
        const int kp = j >> 8, rem = j & 255;
        const int u  = rem >> 2, g4 = rem & 3;
        const int gcol = g4 * 256 + 64 * q + u;
        const float a = rker[(size_t)(2 * kp) * G4H + gcol];
        const float b = rker[(size_t)(2 * kp + 1) * G4H + gcol];
        ws[i] = pack_h2(a, b);
    }
}

extern "C" __global__ void __launch_bounds__(512)
lstm_pers(const float* __restrict__ x, const float* __restrict__ kern,
          u32* __restrict__ ws,
          const float* __restrict__ w1, const float* __restrict__ b1,
          const float* __restrict__ w2, const float* __restrict__ b2,
          float* __restrict__ out)
{
    const int bid = blockIdx.x;
    const int g   = bid & 63;        // group: rows [4g, 4g+4)
    const int q   = bid >> 6;        // member: units [64q, 64q+64)
    const int tid = threadIdx.x;

    const u32* const WG = ws + 512;
    u64*       const HX = (u64*)(ws + 512);  // overlays WG (guarded by barriers)

    // LDS: 131072 + 16384 + 8192 + 4352 = 160,000 B (<=160 KiB, 1 block/CU)
    __shared__ __align__(16) u32 wl[32768];    // rker slice [kp][u][g4]
    __shared__ __align__(16) u32 xzp[4096];    // xz fp16 row-pairs [rp][tc][c]
    __shared__ __align__(16) u32 xs[2048];     // x fp16 f-pairs [fp][r][t]
    __shared__ __align__(16) u32 hpk2[1088];   // h fp16 pairs, 2 bufs x [r*136+kp] (pad: bank-spread)
    float* const hid = (float*)xs;             // head overlay (after final barrier)

    // ---- One-time: weights -> LDS; h(0)=0; two global counter barriers
    {
        const u32* wsrc = WG + q * 32768;
        for (int i = 4 * tid; i < 32768; i += 4 * 512)
            *reinterpret_cast<u32x4*>(&wl[i]) = *reinterpret_cast<const u32x4*>(&wsrc[i]);
    }
    for (int i = tid; i < 1088; i += 512) hpk2[i] = 0;
    __syncthreads();  // all WG reads drained before signalling
    if (tid == 0) {   // barrier 1: every block has consumed WG
        atomicAdd(&ws[0], 1u);
        while (__hip_atomic_load(&ws[0], __ATOMIC_RELAXED, __HIP_MEMORY_SCOPE_AGENT) < 256u) {}
    }
    __syncthreads();
    if (tid < 256) {  // zero OWN HX tag slots, both buffers
        const int bsel = tid >> 7, e = tid & 127;
        __hip_atomic_store(&HX[((size_t)(bsel * 64 + g) * 4 + q) * 128 + e], 0ull,
                           __ATOMIC_RELAXED, __HIP_MEMORY_SCOPE_AGENT);
    }
    __syncthreads();  // zero-stores drained (vmcnt(0) before s_barrier)
    if (tid == 0) {   // barrier 2: every block's tags are clean
        atomicAdd(&ws[1], 1u);
        while (__hip_atomic_load(&ws[1], __ATOMIC_RELAXED, __HIP_MEMORY_SCOPE_AGENT) < 256u) {}
    }
    __syncthreads();

    // Dot-phase mapping: thread = (u, r, h2); unit 64q+u, row 4g+r, K-half h2
    const int u  = tid >> 3;
    const int r  = (tid >> 1) & 3;
    const int hk = tid & 1;
    const int kbase = hk * 64;          // kp in [kbase, kbase+64)
    // Burst mapping (phase A, unchanged from proven r1): (c, half)
    const int bc   = tid & 255;
    const int bhalf = tid >> 8;
    const int bgcol = (bc >> 6) * 256 + 64 * q + (bc & 63);
    // Import mapping: tid in [128,512) -> (partner pi, entry e)
    const int ik = tid - 128;
    const int pp = (ik >> 7) + ((ik >> 7) >= q);
    const int ie = ik & 127;
    float cst = 0.f;                    // cell state: thread (u, r, hk=0)

#pragma unroll 1
    for (int ch = 0; ch < NCH; ++ch) {
        __syncthreads();  // SA0: prev-chunk step reads of xzp/xs done

        // ---- Stage x chunk: xs[fp*32 + r*8 + t]
#pragma unroll
        for (int i = 0; i < 4; ++i) {
            const int slot = tid + i * 512;
            const int rt = slot >> 6, fp = slot & 63;
            const int rr = rt >> 3, tt = rt & 7;
            const f32x2 xv = *reinterpret_cast<const f32x2*>(
                &x[(((size_t)(4 * g + rr)) * TSTEPS + (ch * TC + tt)) * FDIM + 2 * fp]);
            xs[fp * 32 + rr * 8 + tt] = pack_h2(xv[0], xv[1]);
        }
        __syncthreads();  // SA1: xs ready

        // ---- Phase A burst (identical math/order to r1): xz -> xzp
        {
            float acc[4][4];  // [tp][row]
#pragma unroll
            for (int tp = 0; tp < 4; ++tp)
#pragma unroll
                for (int rr = 0; rr < 4; ++rr) acc[tp][rr] = 0.f;
#pragma unroll 4
            for (int fp = 0; fp < 64; ++fp) {
                const float k0 = kern[(size_t)(2 * fp) * G4H + bgcol];
                const float k1 = kern[(size_t)(2 * fp + 1) * G4H + bgcol];
                const h2 wp = h2{(_Float16)k0, (_Float16)k1};
#pragma unroll
                for (int rr = 0; rr < 4; ++rr) {
                    const u32x4 X = *reinterpret_cast<const u32x4*>(&xs[fp * 32 + rr * 8 + bhalf * 4]);
#pragma unroll
                    for (int tp = 0; tp < 4; ++tp)
                        acc[tp][rr] = FDOT2(wp, as_h2(X[tp]), acc[tp][rr]);
                }
            }
#pragma unroll
            for (int tp = 0; tp < 4; ++tp)
#pragma unroll
                for (int rp = 0; rp < 2; ++rp)
                    xzp[rp * 2048 + (bhalf * 4 + tp) * 256 + bc] =
                        pack_h2(acc[tp][2 * rp], acc[tp][2 * rp + 1]);
        }

        // ---- Phase B: 8 steps; ONE barrier per step
#pragma unroll 1
        for (int tc = 0; tc < TC; ++tc) {
            const int t    = ch * TC + tc;
            const int bufC = t & 1, bufN = bufC ^ 1;
            __syncthreads();  // B1: hpk2[bufC] complete; xzp(ch) ready

            // Dot: 4 gate-cols of unit u, row r, K-half hk (ascending kp = r1 order)
            float s0 = 0.f, s1 = 0.f, s2 = 0.f, s3 = 0.f;
#pragma unroll 8
            for (int it = 0; it < 64; ++it) {
                const int kp = kbase + it;
                const u32x4 W = *reinterpret_cast<const u32x4*>(&wl[kp * 256 + u * 4]);
                const h2 hh = as_h2(hpk2[bufC * 544 + r * 136 + kp]);
                s0 = FDOT2(as_h2(W[0]), hh, s0);
                s1 = FDOT2(as_h2(W[1]), hh, s1);
                s2 = FDOT2(as_h2(W[2]), hh, s2);
                s3 = FDOT2(as_h2(W[3]), hh, s3);
            }
            // K-half combine: lane^1 is the other half (half0 + half1, r1 order)
            const float o0 = __shfl_xor(s0, 1), o1 = __shfl_xor(s1, 1);
            const float o2 = __shfl_xor(s2, 1), o3 = __shfl_xor(s3, 1);

            if (hk == 0) {  // gate + export IMMEDIATELY (nothing before export!)
                float z[4];
                z[0] = (s0 + o0); z[1] = (s1 + o1); z[2] = (s2 + o2); z[3] = (s3 + o3);
#pragma unroll
                for (int g4 = 0; g4 < 4; ++g4) {
                    const h2 xp = as_h2(xzp[(r >> 1) * 2048 + tc * 256 + g4 * 64 + u]);
                    z[g4] += (float)((r & 1) ? xp[1] : xp[0]);
                }
                cst = sigmf(z[1]) * cst + sigmf(z[0]) * tanhf_fast(z[2]);
                const float hn = sigmf(z[3]) * tanhf_fast(cst);
                const float ho = __shfl_xor(hn, 8);  // unit u^1, same r, hk=0
                if (!(u & 1)) {
                    const int kpo = 32 * q + (u >> 1);
                    const u32 hv  = pack_h2(hn, ho);
                    hpk2[bufN * 544 + r * 136 + kpo] = hv;  // own slice, local
                    const int e = (u >> 1) * 4 + r;
                    __hip_atomic_store(&HX[((size_t)(bufN * 64 + g) * 4 + q) * 128 + e],
                                       ((u64)(u32)(t + 1) << 32) | (u64)hv,
                                       __ATOMIC_RELAXED, __HIP_MEMORY_SCOPE_AGENT);
                }
            }
            if (tid >= 128) {  // import: poll tag-in-word, then LDS write
                const u64* src = &HX[((size_t)(bufN * 64 + g) * 4 + pp) * 128 + ie];
                u64 v;
                do {
                    v = __hip_atomic_load(src, __ATOMIC_RELAXED, __HIP_MEMORY_SCOPE_AGENT);
                } while ((u32)(v >> 32) < (u32)(t + 1));
                hpk2[bufN * 544 + (ie & 3) * 136 + 32 * pp + (ie >> 2)] = (u32)v;
            }
            // next B1 orders hpk2[bufN] writes vs reads
        }
    }
    __syncthreads();  // h(512) in hpk2 buf 0 complete

    // ---- Fused head: member q emits out[4g+q] using ROW q of the group's h
    if (tid < 100) {
        float aa = b1[tid];
        const _Float16* hph = (const _Float16*)hpk2;  // buf 0
#pragma unroll 8
        for (int k = 0; k < HDIM; ++k)
            aa += (float)hph[(q * 136 + (k >> 1)) * 2 + (k & 1)] * w1[k * 100 + tid];
        hid[tid] = fmaxf(aa, 0.f);
    }
    __syncthreads();
    if (tid == 0) {
        float v = b2[0];
#pragma unroll 4
        for (int j = 0; j < 100; ++j) v += hid[j] * w2[j];
        out[4 * g + q] = v;
    }
}

extern "C" void kernel_launch(void* const* d_in, const int* in_sizes, int n_in,
                              void* d_out, int out_size, void* d_ws, size_t ws_size,
                              hipStream_t stream)
{
    const float* x    = (const float*)d_in[0];
    const float* kern = (const float*)d_in[1];
    const float* rker = (const float*)d_in[2];
    const float* w1   = (const float*)d_in[3];
    const float* b1   = (const float*)d_in[4];
    const float* w2   = (const float*)d_in[5];
    const float* b2   = (const float*)d_in[6];
    u32* ws = (u32*)d_ws;  // 2 KB hdr + 512 KB (WG/HX overlay) < 768 KB proven

    conv_wpk<<<dim3(514), dim3(256), 0, stream>>>(rker, ws);
    lstm_pers<<<dim3(256), dim3(512), 0, stream>>>(x, kern, ws, w1, b1, w2, b2, (float*)d_out);
}

// Round 4
// 2281.267 us; speedup vs baseline: 1.7302x; 1.1153x over previous
//
#include <hip/hip_runtime.h>

// Dims
constexpr int TSTEPS = 512;
constexpr int FDIM   = 128;
constexpr int HDIM   = 256;
constexpr int G4H    = 1024;   // 4*H
constexpr int TC     = 8;      // time-chunk (xz granularity)
constexpr int NCH    = TSTEPS / TC;

typedef float        f32x2 __attribute__((ext_vector_type(2)));
typedef _Float16     h2    __attribute__((ext_vector_type(2)));
typedef unsigned int u32;
typedef unsigned long long u64;
typedef u32          u32x2 __attribute__((ext_vector_type(2)));
typedef u32          u32x4 __attribute__((ext_vector_type(4)));

#if defined(__has_builtin)
#if __has_builtin(__builtin_amdgcn_fdot2)
#define FDOT2(a, b, c) __builtin_amdgcn_fdot2((a), (b), (c), false)
#endif
#endif
#ifndef FDOT2
#define FDOT2(a, b, c) ((c) + (float)(a)[0] * (float)(b)[0] + (float)(a)[1] * (float)(b)[1])
#endif

__device__ __forceinline__ h2 as_h2(u32 v) { union { u32 u; h2 p; } c; c.u = v; return c.p; }
__device__ __forceinline__ u32 pack_h2(float a, float b) {
    union { h2 p; u32 u; } c; c.p = h2{(_Float16)a, (_Float16)b}; return c.u;
}
__device__ __forceinline__ float sigmf(float z) { return 1.f / (1.f + __expf(-z)); }
__device__ __forceinline__ float tanhf_fast(float z) {
    float a = fabsf(z);
    float e = __expf(-2.f * a);
    float r = (1.f - e) / (1.f + e);
    return z < 0.f ? -r : r;
}

// ws layout (u32): [0],[1]=startup counters, [512..) WG = repacked rker
// (4 members x 32768 u32 = 512 KB). HX (65536 u64 = 512 KB) EXACTLY overlays
// WG — safe: WG fully consumed before counter-barrier 1; HX tag slots zeroed
// before counter-barrier 2; only then does any block poll.
// HX entry = u64 { lo: h fp16 pair, hi: tag = t+1 } (tag+data one word).
//
// WG layout per member q: wl[kp(128)][u(64)][g4(4)] u32 = fp16 pair
// (rker[2kp][gcol], rker[2kp+1][gcol]), gcol = g4*256 + 64q + u.
//
// Dot mapping (v4): thread = (u = tid>>3, ks = tid&7). kp = i*8 + ks, 16 i's.
// W b128 per (kp,u): 64 DISTINCT lane addresses (dense, zero redundancy —
// r3's 4x r-redundant broadcast b128s were the LDS-port bottleneck).
// H b128 per kp: 8 distinct addresses spread across all 32 banks (kp*4 mod 32
// = 4ks), 8-lane broadcast each. K-partials reduced in-wave (shfl tree),
// row r=ks lands in lanes ks<4 which gate + export as in r3.

extern "C" __global__ void __launch_bounds__(256)
conv_wpk(const float* __restrict__ rker, u32* __restrict__ ws)
{
    for (int i = blockIdx.x * 256 + threadIdx.x; i < 512 + 4 * 32768; i += gridDim.x * 256) {
        if (i < 512) { ws[i] = 0; continue; }   // zero counters (every launch)
        const int ii = i - 512;
        const int q  = ii >> 15, j = ii & 32767;
        const int kp = j >> 8, rem = j & 255;
        const int u  = rem >> 2, g4 = rem & 3;
        const int gcol = g4 * 256 + 64 * q + u;
        const float a = rker[(size_t)(2 * kp) * G4H + gcol];
        const float b = rker[(size_t)(2 * kp + 1) * G4H + gcol];
        ws[i] = pack_h2(a, b);
    }
}

// xs XOR swizzle: word (fp*32 + rr*8 + tt) ^ ((fp&7)<<2). Keeps 16B alignment
// (bits 0-1 untouched); spreads the staging write (was 64-way same-bank) 8-way.
__device__ __forceinline__ int xs_idx(int fp, int rr, int tt) {
    return (fp * 32 + rr * 8 + tt) ^ ((fp & 7) << 2);
}

extern "C" __global__ void __launch_bounds__(512)
lstm_pers(const float* __restrict__ x, const float* __restrict__ kern,
          u32* __restrict__ ws,
          const float* __restrict__ w1, const float* __restrict__ b1,
          const float* __restrict__ w2, const float* __restrict__ b2,
          float* __restrict__ out)
{
    const int bid = blockIdx.x;
    const int g   = bid & 63;        // group: rows [4g, 4g+4)
    const int q   = bid >> 6;        // member: units [64q, 64q+64)
    const int tid = threadIdx.x;

    const u32* const WG = ws + 512;
    u64*       const HX = (u64*)(ws + 512);  // overlays WG (guarded by barriers)

    // LDS: 131072 + 16384 + 8192 + 4096 = 159,744 B (<=160 KiB, 1 block/CU)
    __shared__ __align__(16) u32 wl[32768];    // rker slice [kp][u][g4]
    __shared__ __align__(16) u32 xzp[4096];    // xz fp16 row-pairs [rp][tc][c]
    __shared__ __align__(16) u32 xs[2048];     // x fp16 f-pairs, XOR-swizzled
    __shared__ __align__(16) u32 hpk2[1024];   // h fp16 pairs, 2 bufs x [kp][r]
    float* const hid = (float*)xs;             // head overlay (after final barrier)

    // ---- One-time: weights -> LDS; h(0)=0; two global counter barriers
    {
        const u32* wsrc = WG + q * 32768;
        for (int i = 4 * tid; i < 32768; i += 4 * 512)
            *reinterpret_cast<u32x4*>(&wl[i]) = *reinterpret_cast<const u32x4*>(&wsrc[i]);
    }
    for (int i = tid; i < 1024; i += 512) hpk2[i] = 0;
    __syncthreads();  // all WG reads drained before signalling
    if (tid == 0) {   // barrier 1: every block has consumed WG
        atomicAdd(&ws[0], 1u);
        while (__hip_atomic_load(&ws[0], __ATOMIC_RELAXED, __HIP_MEMORY_SCOPE_AGENT) < 256u) {}
    }
    __syncthreads();
    if (tid < 256) {  // zero OWN HX tag slots, both buffers
        const int bsel = tid >> 7, e = tid & 127;
        __hip_atomic_store(&HX[((size_t)(bsel * 64 + g) * 4 + q) * 128 + e], 0ull,
                           __ATOMIC_RELAXED, __HIP_MEMORY_SCOPE_AGENT);
    }
    __syncthreads();  // zero-stores drained (vmcnt(0) before s_barrier)
    if (tid == 0) {   // barrier 2: every block's tags are clean
        atomicAdd(&ws[1], 1u);
        while (__hip_atomic_load(&ws[1], __ATOMIC_RELAXED, __HIP_MEMORY_SCOPE_AGENT) < 256u) {}
    }
    __syncthreads();

    // Dot-phase mapping: thread = (u, ks); unit 64q+u, K-subset kp == i*8+ks
    const int u  = tid >> 3;
    const int ks = tid & 7;
    // Phase-A burst mapping (proven r1/r3): (c, half)
    const int bc    = tid & 255;
    const int bhalf = tid >> 8;
    const int bgcol = (bc >> 6) * 256 + 64 * q + (bc & 63);
    // Import mapping: tid in [128,512) -> (partner pp, entry ie)
    const int ik = tid - 128;
    const int pp = (ik >> 7) + ((ik >> 7) >= q);
    const int ie = ik & 127;
    float cst = 0.f;   // cell state: lanes ks<4 hold (unit u, row ks)

#pragma unroll 1
    for (int ch = 0; ch < NCH; ++ch) {
        __syncthreads();  // SA0: prev-chunk step reads of xzp/xs done

        // ---- Stage x chunk: xs (swizzled)
#pragma unroll
        for (int i = 0; i < 4; ++i) {
            const int slot = tid + i * 512;
            const int rt = slot >> 6, fp = slot & 63;
            const int rr = rt >> 3, tt = rt & 7;
            const f32x2 xv = *reinterpret_cast<const f32x2*>(
                &x[(((size_t)(4 * g + rr)) * TSTEPS + (ch * TC + tt)) * FDIM + 2 * fp]);
            xs[xs_idx(fp, rr, tt)] = pack_h2(xv[0], xv[1]);
        }
        __syncthreads();  // SA1: xs ready

        // ---- Phase A burst (identical math/order to r3): xz -> xzp
        {
            float acc[4][4];  // [tp][row]
#pragma unroll
            for (int tp = 0; tp < 4; ++tp)
#pragma unroll
                for (int rr = 0; rr < 4; ++rr) acc[tp][rr] = 0.f;
#pragma unroll 4
            for (int fp = 0; fp < 64; ++fp) {
                const float k0 = kern[(size_t)(2 * fp) * G4H + bgcol];
                const float k1 = kern[(size_t)(2 * fp + 1) * G4H + bgcol];
                const h2 wp = h2{(_Float16)k0, (_Float16)k1};
#pragma unroll
                for (int rr = 0; rr < 4; ++rr) {
                    const u32x4 X = *reinterpret_cast<const u32x4*>(&xs[xs_idx(fp, rr, bhalf * 4)]);
#pragma unroll
                    for (int tp = 0; tp < 4; ++tp)
                        acc[tp][rr] = FDOT2(wp, as_h2(X[tp]), acc[tp][rr]);
                }
            }
#pragma unroll
            for (int tp = 0; tp < 4; ++tp)
#pragma unroll
                for (int rp = 0; rp < 2; ++rp)
                    xzp[rp * 2048 + (bhalf * 4 + tp) * 256 + bc] =
                        pack_h2(acc[tp][2 * rp], acc[tp][2 * rp + 1]);
        }

        // ---- Phase B: 8 steps; ONE barrier per step
#pragma unroll 1
        for (int tc = 0; tc < TC; ++tc) {
            const int t    = ch * TC + tc;
            const int bufC = t & 1, bufN = bufC ^ 1;
            __syncthreads();  // B1: hpk2[bufC] complete; xzp(ch) ready

            // Dot: acc[g][r] for unit u over this lane's 16 kp (dense W reads)
            float acc[4][4];
#pragma unroll
            for (int gg = 0; gg < 4; ++gg)
#pragma unroll
                for (int rr = 0; rr < 4; ++rr) acc[gg][rr] = 0.f;
#pragma unroll 4
            for (int i = 0; i < 16; ++i) {
                const int kp = i * 8 + ks;
                const u32x4 W  = *reinterpret_cast<const u32x4*>(&wl[kp * 256 + u * 4]);
                const u32x4 Hh = *reinterpret_cast<const u32x4*>(&hpk2[bufC * 512 + kp * 4]);
#pragma unroll
                for (int gg = 0; gg < 4; ++gg) {
                    const h2 wg = as_h2(W[gg]);
                    acc[gg][0] = FDOT2(wg, as_h2(Hh[0]), acc[gg][0]);
                    acc[gg][1] = FDOT2(wg, as_h2(Hh[1]), acc[gg][1]);
                    acc[gg][2] = FDOT2(wg, as_h2(Hh[2]), acc[gg][2]);
                    acc[gg][3] = FDOT2(wg, as_h2(Hh[3]), acc[gg][3]);
                }
            }

            // Reduce-scatter over ks (3 rounds): row r=ks lands in lanes ks<4
            const bool kb0 = (ks & 1), kb1 = (ks & 2);
            float v0[4], v1[4];  // rows (ks&1), (ks&1)+2
#pragma unroll
            for (int gg = 0; gg < 4; ++gg) {
                const float give0 = kb0 ? acc[gg][0] : acc[gg][1];
                const float give1 = kb0 ? acc[gg][2] : acc[gg][3];
                const float got0 = __shfl_xor(give0, 1);
                const float got1 = __shfl_xor(give1, 1);
                v0[gg] = (kb0 ? acc[gg][1] : acc[gg][0]) + got0;
                v1[gg] = (kb0 ? acc[gg][3] : acc[gg][2]) + got1;
            }
            float w4[4];  // row ks&3
#pragma unroll
            for (int gg = 0; gg < 4; ++gg) {
                const float give = kb1 ? v0[gg] : v1[gg];
                const float got  = __shfl_xor(give, 2);
                w4[gg] = (kb1 ? v1[gg] : v0[gg]) + got;
            }
#pragma unroll
            for (int gg = 0; gg < 4; ++gg) w4[gg] += __shfl_xor(w4[gg], 4);

            if (ks < 4) {  // gate + export IMMEDIATELY; row r = ks
                const int r = ks;
                float z[4];
#pragma unroll
                for (int g4 = 0; g4 < 4; ++g4) {
                    const h2 xp = as_h2(xzp[(r >> 1) * 2048 + tc * 256 + g4 * 64 + u]);
                    z[g4] = w4[g4] + (float)((r & 1) ? xp[1] : xp[0]);
                }
                cst = sigmf(z[1]) * cst + sigmf(z[0]) * tanhf_fast(z[2]);
                const float hn = sigmf(z[3]) * tanhf_fast(cst);
                const float ho = __shfl_xor(hn, 8);  // unit u^1, same (ks=r)
                if (!(u & 1)) {
                    const int kpo = 32 * q + (u >> 1);
                    const u32 hv  = pack_h2(hn, ho);
                    hpk2[bufN * 512 + kpo * 4 + r] = hv;  // own slice, local
                    const int e = (u >> 1) * 4 + r;
                    __hip_atomic_store(&HX[((size_t)(bufN * 64 + g) * 4 + q) * 128 + e],
                                       ((u64)(u32)(t + 1) << 32) | (u64)hv,
                                       __ATOMIC_RELAXED, __HIP_MEMORY_SCOPE_AGENT);
                }
            }
            if (tid >= 128) {  // import: poll tag-in-word, then LDS write (stride-1)
                const u64* src = &HX[((size_t)(bufN * 64 + g) * 4 + pp) * 128 + ie];
                u64 v;
                do {
                    v = __hip_atomic_load(src, __ATOMIC_RELAXED, __HIP_MEMORY_SCOPE_AGENT);
                } while ((u32)(v >> 32) < (u32)(t + 1));
                hpk2[bufN * 512 + 128 * pp + ie] = (u32)v;
            }
            // next B1 orders hpk2[bufN] writes vs reads
        }
    }
    __syncthreads();  // h(512) complete in hpk2 buf 0

    // ---- Fused head: member q emits out[4g+q] using ROW q of the group's h
    if (tid < 100) {
        float aa = b1[tid];
        const _Float16* hph = (const _Float16*)hpk2;  // buf 0: [kp][r] pairs
#pragma unroll 8
        for (int k = 0; k < HDIM; ++k)
            aa += (float)hph[((k >> 1) * 4 + q) * 2 + (k & 1)] * w1[k * 100 + tid];
        hid[tid] = fmaxf(aa, 0.f);
    }
    __syncthreads();
    if (tid == 0) {
        float v = b2[0];
#pragma unroll 4
        for (int j = 0; j < 100; ++j) v += hid[j] * w2[j];
        out[4 * g + q] = v;
    }
}

extern "C" void kernel_launch(void* const* d_in, const int* in_sizes, int n_in,
                              void* d_out, int out_size, void* d_ws, size_t ws_size,
                              hipStream_t stream)
{
    const float* x    = (const float*)d_in[0];
    const float* kern = (const float*)d_in[1];
    const float* rker = (const float*)d_in[2];
    const float* w1   = (const float*)d_in[3];
    const float* b1   = (const float*)d_in[4];
    const float* w2   = (const float*)d_in[5];
    const float* b2   = (const float*)d_in[6];
    u32* ws = (u32*)d_ws;  // 2 KB hdr + 512 KB (WG/HX overlay) < 768 KB proven

    conv_wpk<<<dim3(514), dim3(256), 0, stream>>>(rker, ws);
    lstm_pers<<<dim3(256), dim3(512), 0, stream>>>(x, kern, ws, w1, b1, w2, b2, (float*)d_out);
}